// Round 18
// baseline (548.073 us; speedup 1.0000x reference)
//
#include <hip/hip_runtime.h>
#include <hip/hip_bf16.h>
#include <math.h>

#define BB 2
#define HWp 4096
#define CH 64
#define CIN 128
#define EE 192
#define DIN 384
#define DST 4
#define DTR 12
#define KC 4
#define NCc 9
#define SAMPLE 2048
#define LEc 2048
#define NCH 128
#define CLEN 16
#define NSPLIT 8
#define PADW 70
#define PADP 3
#define NTICK 64

typedef __attribute__((ext_vector_type(8))) short bf16x8;
typedef __attribute__((ext_vector_type(4))) float f32x4;

__device__ __forceinline__ float sigmoid_fast(float x){ return 1.0f/(1.0f+__expf(-x)); }
__device__ __forceinline__ float softplus_f(float x){ return fmaxf(x,0.0f) + log1pf(expf(-fabsf(x))); }

__device__ __forceinline__ void split_bf16(float v, unsigned short& h, unsigned short& l){
  __hip_bfloat16 bh = __float2bfloat16(v);
  h = *(unsigned short*)&bh;
  float r = v - __bfloat162float(bh);
  __hip_bfloat16 bl = __float2bfloat16(r);
  l = *(unsigned short*)&bl;
}

// ---------------- weight prep + zero fills ----------------
#define SZ_WTBLK_BF (2*9*EE*EE)
#define SZ_WTHEAD_BF (9*EE*EE)
#define SZ_WTIN (2*EE*2*DIN)
#define SZ_WTOUT (2*DIN*EE)
#define SZ_WTC0 (CIN*EE)
#define SZ_WT_TOTAL (SZ_WTBLK_BF+SZ_WTHEAD_BF+SZ_WTIN+SZ_WTOUT+SZ_WTC0)
#define NXPI (BB*PADW*PADW*EE/2)
#define NRANKS (BB*HWp)

__global__ void prep_weights(const float* blk_w, const float* head_w, const float* in_w,
                             const float* out_w, const float* c0_w,
                             __hip_bfloat16* wtb_blk, __hip_bfloat16* wtb_head,
                             unsigned short* wtb_in_hi, unsigned short* wtb_in_lo,
                             unsigned short* wtb_out_hi, unsigned short* wtb_out_lo,
                             unsigned short* wtc0_hi, unsigned short* wtc0_lo,
                             int* xpad_i, int* ranks, int* tickets){
  int i = blockIdx.x*256 + threadIdx.x;
  if (i >= SZ_WT_TOTAL + NXPI + NRANKS + NTICK) return;
  int o = i;
  if (o < SZ_WTBLK_BF){
    int j = o & 7;
    int lane = (o>>3) & 63;
    int nt = (o/512) % 3;
    int e = (o/1536) % 6;
    int tap = (o/9216) % 9;
    int eoB = (o/82944) % 4;
    int d = o / 331776;
    int m = lane & 15, kg = lane >> 4;
    int eo = eoB*48 + nt*16 + m;
    int ei = e*32 + kg*8 + j;
    wtb_blk[o] = __float2bfloat16(blk_w[(((d*EE+eo)*EE+ei)*9)+tap]);
    return;
  }
  o -= SZ_WTBLK_BF;
  if (o < SZ_WTHEAD_BF){
    int j = o & 7;
    int lane = (o>>3) & 63;
    int nt = (o/512) % 3;
    int e = (o/1536) % 6;
    int tap = (o/9216) % 9;
    int eoB = (o/82944) % 4;
    int m = lane & 15, kg = lane >> 4;
    int eo = eoB*48 + nt*16 + m;
    int ei = e*32 + kg*8 + j;
    wtb_head[o] = __float2bfloat16(head_w[((eo*EE+ei)*9)+tap]);
    return;
  }
  o -= SZ_WTHEAD_BF;
  if (o < SZ_WTIN){
    int j = o & 7;
    int lane = (o>>3) & 63;
    int ks = (o/512) % 6;
    int nt = (o/3072) % 48;
    int d = o / 147456;
    int m = lane & 15, kg = lane >> 4;
    int dd = nt*16 + m;
    int ei = ks*32 + kg*8 + j;
    float v = in_w[((size_t)(d*768)+dd)*EE + ei];
    unsigned short hh, ll; split_bf16(v, hh, ll);
    wtb_in_hi[o] = hh; wtb_in_lo[o] = ll;
    return;
  }
  o -= SZ_WTIN;
  if (o < SZ_WTOUT){
    int j = o & 7;
    int lane = (o>>3) & 63;
    int ks = (o/512) % 12;
    int nt = (o/6144) % 12;
    int d = o / 73728;
    int m = lane & 15, kg = lane >> 4;
    int eo = nt*16 + m;
    int dch = ks*32 + kg*8 + j;
    float v = out_w[((size_t)(d*EE)+eo)*DIN + dch];
    unsigned short hh, ll; split_bf16(v, hh, ll);
    wtb_out_hi[o] = hh; wtb_out_lo[o] = ll;
    return;
  }
  o -= SZ_WTOUT;
  if (o < SZ_WTC0){
    int j = o & 7;
    int lane = (o>>3) & 63;
    int ks = (o/512) % 4;
    int nt = o / 2048;
    int m = lane & 15, kg = lane >> 4;
    int e = nt*16 + m;
    int c = ks*32 + kg*8 + j;
    float v = c0_w[e*CIN + c];
    unsigned short hh, ll; split_bf16(v, hh, ll);
    wtc0_hi[o] = hh; wtc0_lo[o] = ll;
    return;
  }
  o -= SZ_WTC0;
  if (o < NXPI){ xpad_i[o] = 0; return; }
  o -= NXPI;
  if (o < NRANKS){ ranks[o] = 0; return; }
  o -= NRANKS;
  tickets[o] = 0;
}

// ---------------- stage 1: res^2, feats(+bf16 hi/lo), simple_pred, scores ----------------
__global__ __launch_bounds__(256) void k_prep2(const float* __restrict__ x, const float* sp_w,
                       const float* sp_b, float* __restrict__ res2, float* __restrict__ feats,
                       unsigned short* __restrict__ fhi, unsigned short* __restrict__ flo,
                       float* scores, float* outSP){
  __shared__ float tile[CIN][33];
  int t = threadIdx.x;
  int p0 = blockIdx.x * 32;             // grid BB*HWp/32 = 256 blocks
  int b = p0 >> 12; int prow = p0 & 4095;
  const float* xb = x + (size_t)b*CIN*HWp + prow;
  #pragma unroll
  for (int i=0;i<4;i++){
    int idx = i*256 + t;
    int c = idx >> 3;            // 0..127
    int p4 = idx & 7;            // 8 float4 per row
    float4 v = *(const float4*)(xb + (size_t)c*HWp + p4*4);
    tile[c][p4*4+0]=v.x; tile[c][p4*4+1]=v.y; tile[c][p4*4+2]=v.z; tile[c][p4*4+3]=v.w;
  }
  __syncthreads();
  int lane = t & 63;
  int wv = t >> 6;
  float sw = sp_w[lane];
  float sb = sp_b[0];
  #pragma unroll
  for (int k=0;k<8;k++){
    int p = wv*8 + k;
    float v = tile[lane][p];
    float r2 = v*v;
    float f = tile[64+lane][p];
    int g = p0 + p;
    res2[(size_t)g*CH + lane] = r2;
    feats[(size_t)g*CH + lane] = f;
    unsigned short hh, ll;
    split_bf16(f, hh, ll);
    fhi[(size_t)g*CH + lane] = hh;
    flo[(size_t)g*CH + lane] = ll;
    float aS = r2*sw, aM = r2;
    #pragma unroll
    for (int msk=32; msk>0; msk>>=1){
      aS += __shfl_xor(aS, msk, 64);
      aM += __shfl_xor(aM, msk, 64);
    }
    if (lane == 0){
      float sp = 1.0f/(1.0f+expf(-(aS + sb)));
      outSP[g] = sp;
      scores[g] = sp + aM*(1.0f/CH);
    }
  }
}

// ---------------- ranks (2D partial + atomics) + last-block builds idx_sorted/easy ----------------
__global__ __launch_bounds__(256) void k_rank2(const float* scores, int* ranks, int* ticket,
                                               int* idx_sorted, int* easy_idx){
  int b = blockIdx.z;
  int t = threadIdx.x;
  int p = blockIdx.x*256 + t;
  int j0 = blockIdx.y*256;
  __shared__ float s[256];
  s[t] = scores[b*HWp + j0 + t];
  float sp = scores[b*HWp + p];
  __syncthreads();
  int r = 0;
  #pragma unroll 8
  for (int jj=0;jj<256;jj++){
    float sj = s[jj];
    int j = j0 + jj;
    r += (sj < sp || (sj == sp && j < p)) ? 1 : 0;
  }
  atomicAdd(&ranks[b*HWp+p], r);
  __threadfence();
  __syncthreads();
  __shared__ int amlast;
  if (t == 0){
    int total = gridDim.x*gridDim.y*gridDim.z;
    amlast = (atomicAdd(ticket, 1) == total - 1) ? 1 : 0;
  }
  __syncthreads();
  if (!amlast) return;
  __threadfence();
  // easy/idx_sorted build on this single block (256 threads, 16 elems each, both batches)
  int lane = t & 63, wv = t >> 6;
  __shared__ int wsum[4], woff[4];
  for (int bb=0; bb<BB; bb++){
    int i0 = t*16;
    int cnt = 0;
    #pragma unroll
    for (int u=0;u<16;u++){
      int rr = ranks[bb*HWp + i0 + u];
      if (rr < SAMPLE) idx_sorted[bb*SAMPLE + rr] = i0 + u;
      else cnt++;
    }
    int inc = cnt;
    #pragma unroll
    for (int off=1; off<64; off<<=1){
      int v = __shfl_up(inc, off, 64);
      if (lane >= off) inc += v;
    }
    if (lane == 63) wsum[wv] = inc;
    __syncthreads();
    if (t == 0){
      int acc = 0;
      #pragma unroll
      for (int i2=0;i2<4;i2++){ woff[i2] = acc; acc += wsum[i2]; }
    }
    __syncthreads();
    int pre = woff[wv] + inc - cnt;
    #pragma unroll
    for (int u=0;u<16;u++){
      int rr = ranks[bb*HWp + i0 + u];
      if (rr >= SAMPLE) easy_idx[bb*LEc + (pre++)] = i0 + u;
    }
    __syncthreads();
  }
}

// ---------------- bank: norms + gathered bf16 hi/lo rows ----------------
__global__ __launch_bounds__(64) void k_bank(const float* __restrict__ feats, const int* __restrict__ idx_sorted,
                       float* __restrict__ bnorm, unsigned short* __restrict__ bankhi,
                       unsigned short* __restrict__ banklo){
  int t = blockIdx.x*64+threadIdx.x;  // B*SAMPLE, grid 64
  int b = t>>11;
  int row = idx_sorted[t];
  const float4* fr = (const float4*)(feats + (size_t)(b*HWp + row)*CH);
  ushort4* oh = (ushort4*)(bankhi + (size_t)t*CH);
  ushort4* ol = (ushort4*)(banklo + (size_t)t*CH);
  float s=0;
  #pragma unroll
  for (int k=0;k<16;k++){
    float4 v = fr[k];
    s += v.x*v.x+v.y*v.y+v.z*v.z+v.w*v.w;
    ushort4 h, l;
    split_bf16(v.x, h.x, l.x);
    split_bf16(v.y, h.y, l.y);
    split_bf16(v.z, h.z, l.z);
    split_bf16(v.w, h.w, l.w);
    oh[k] = h; ol[k] = l;
  }
  bnorm[t] = s;
}

// ---------------- NN search via split-bf16 MFMA ----------------
__global__ __launch_bounds__(256) void k_nn_mfma(const unsigned short* __restrict__ fhi,
        const unsigned short* __restrict__ flo, const unsigned short* __restrict__ bankhi,
        const unsigned short* __restrict__ banklo, const float* __restrict__ bnorm,
        const int* __restrict__ idx_sorted, float* __restrict__ pval, int* __restrict__ pidx){
  int lane = threadIdx.x & 63;
  int wv = threadIdx.x >> 6;
  int m = lane & 15, kg = lane >> 4;
  int b = blockIdx.z;
  int qrel0 = blockIdx.x*64 + wv*16;
  int jsplit = blockIdx.y;
  const short* qh = (const short*)fhi + ((size_t)(b*HWp + qrel0 + m))*CH + kg*8;
  const short* ql = (const short*)flo + ((size_t)(b*HWp + qrel0 + m))*CH + kg*8;
  bf16x8 Ah0 = *(const bf16x8*)(qh);
  bf16x8 Ah1 = *(const bf16x8*)(qh + 32);
  bf16x8 Al0 = *(const bf16x8*)(ql);
  bf16x8 Al1 = *(const bf16x8*)(ql + 32);
  float best0=1e30f,best1=1e30f,best2=1e30f,best3=1e30f;
  int bj0=0,bj1=0,bj2=0,bj3=0;
  for (int jt=0; jt<16; jt++){
    int jb = jsplit*256 + jt*16;
    int j = jb + m;
    const short* bh = (const short*)bankhi + ((size_t)(b*SAMPLE + j))*CH + kg*8;
    const short* bl = (const short*)banklo + ((size_t)(b*SAMPLE + j))*CH + kg*8;
    bf16x8 Bh0 = *(const bf16x8*)(bh);
    bf16x8 Bh1 = *(const bf16x8*)(bh + 32);
    bf16x8 Bl0 = *(const bf16x8*)(bl);
    bf16x8 Bl1 = *(const bf16x8*)(bl + 32);
    f32x4 acc = {0,0,0,0};
    acc = __builtin_amdgcn_mfma_f32_16x16x32_bf16(Ah0, Bh0, acc, 0,0,0);
    acc = __builtin_amdgcn_mfma_f32_16x16x32_bf16(Ah1, Bh1, acc, 0,0,0);
    acc = __builtin_amdgcn_mfma_f32_16x16x32_bf16(Al0, Bh0, acc, 0,0,0);
    acc = __builtin_amdgcn_mfma_f32_16x16x32_bf16(Al1, Bh1, acc, 0,0,0);
    acc = __builtin_amdgcn_mfma_f32_16x16x32_bf16(Ah0, Bl0, acc, 0,0,0);
    acc = __builtin_amdgcn_mfma_f32_16x16x32_bf16(Ah1, Bl1, acc, 0,0,0);
    acc = __builtin_amdgcn_mfma_f32_16x16x32_bf16(Al0, Bl0, acc, 0,0,0);
    acc = __builtin_amdgcn_mfma_f32_16x16x32_bf16(Al1, Bl1, acc, 0,0,0);
    float bn = bnorm[b*SAMPLE + j];
    int src = idx_sorted[b*SAMPLE + j];
    float v0 = bn - 2.0f*acc[0];
    float v1 = bn - 2.0f*acc[1];
    float v2 = bn - 2.0f*acc[2];
    float v3 = bn - 2.0f*acc[3];
    int qp = qrel0 + kg*4;
    if (src != qp   && v0 < best0){ best0 = v0; bj0 = j; }
    if (src != qp+1 && v1 < best1){ best1 = v1; bj1 = j; }
    if (src != qp+2 && v2 < best2){ best2 = v2; bj2 = j; }
    if (src != qp+3 && v3 < best3){ best3 = v3; bj3 = j; }
  }
  #pragma unroll
  for (int mask=1; mask<16; mask<<=1){
    float ov; int oj;
    ov = __shfl_xor(best0, mask, 64); oj = __shfl_xor(bj0, mask, 64);
    if (ov < best0 || (ov == best0 && oj < bj0)){ best0 = ov; bj0 = oj; }
    ov = __shfl_xor(best1, mask, 64); oj = __shfl_xor(bj1, mask, 64);
    if (ov < best1 || (ov == best1 && oj < bj1)){ best1 = ov; bj1 = oj; }
    ov = __shfl_xor(best2, mask, 64); oj = __shfl_xor(bj2, mask, 64);
    if (ov < best2 || (ov == best2 && oj < bj2)){ best2 = ov; bj2 = oj; }
    ov = __shfl_xor(best3, mask, 64); oj = __shfl_xor(bj3, mask, 64);
    if (ov < best3 || (ov == best3 && oj < bj3)){ best3 = ov; bj3 = oj; }
  }
  if (m == 0){
    int qg = b*HWp + qrel0 + kg*4;
    pval[(qg+0)*NSPLIT + jsplit] = best0; pidx[(qg+0)*NSPLIT + jsplit] = bj0;
    pval[(qg+1)*NSPLIT + jsplit] = best1; pidx[(qg+1)*NSPLIT + jsplit] = bj1;
    pval[(qg+2)*NSPLIT + jsplit] = best2; pidx[(qg+2)*NSPLIT + jsplit] = bj2;
    pval[(qg+3)*NSPLIT + jsplit] = best3; pidx[(qg+3)*NSPLIT + jsplit] = bj3;
  }
}

// ---------------- 1x1 conv c0 via split-bf16 MFMA + fused NN resolve ----------------
__global__ __launch_bounds__(256) void k_c0(const float* __restrict__ res2, const float* __restrict__ feats,
        const int* idx_sorted, const float* pval, const int* pidx,
        const unsigned short* __restrict__ wthi, const unsigned short* __restrict__ wtlo,
        const float* c0_b, float* __restrict__ hidden){
  int lane = threadIdx.x & 63, wv = threadIdx.x >> 6;
  int m = lane & 15, kg = lane >> 4;
  int base = blockIdx.x*64 + wv*16;    // grid.x = BB*HWp/64 = 128
  int b = base >> 12;
  int nq = blockIdx.y;
  int px = base + m;
  float best = 1e30f; int bj = 0;
  #pragma unroll
  for (int s=0;s<NSPLIT;s++){
    float v = pval[px*NSPLIT+s]; int j = pidx[px*NSPLIT+s];
    if (v < best){ best = v; bj = j; }
  }
  int brow = idx_sorted[b*SAMPLE + bj];
  bf16x8 Ah[4], Al[4];
  #pragma unroll
  for (int ks=0; ks<4; ks++){
    int k0 = ks*32 + kg*8;
    #pragma unroll
    for (int q=0;q<8;q++){
      int k = k0 + q;
      float v;
      if (k < CH) v = res2[(size_t)px*CH + k];
      else {
        int cc = k - CH;
        float a = feats[(size_t)(b*HWp + brow)*CH + cc];
        float f = feats[(size_t)px*CH + cc];
        float d = a - f; v = d*d;
      }
      unsigned short hh, ll; split_bf16(v, hh, ll);
      Ah[ks][q] = (short)hh; Al[ks][q] = (short)ll;
    }
  }
  const short* wh = (const short*)wthi;
  const short* wl = (const short*)wtlo;
  for (int ntile=0; ntile<3; ntile++){
    int nt = nq*3 + ntile;
    const short* ph = wh + (size_t)nt*2048 + lane*8;
    const short* pl = wl + (size_t)nt*2048 + lane*8;
    f32x4 acc = {0,0,0,0};
    #pragma unroll
    for (int ks=0; ks<4; ks++){
      bf16x8 Bh = *(const bf16x8*)(ph + ks*512);
      bf16x8 Bl = *(const bf16x8*)(pl + ks*512);
      acc = __builtin_amdgcn_mfma_f32_16x16x32_bf16(Ah[ks], Bh, acc, 0,0,0);
      acc = __builtin_amdgcn_mfma_f32_16x16x32_bf16(Al[ks], Bh, acc, 0,0,0);
      acc = __builtin_amdgcn_mfma_f32_16x16x32_bf16(Ah[ks], Bl, acc, 0,0,0);
      acc = __builtin_amdgcn_mfma_f32_16x16x32_bf16(Al[ks], Bl, acc, 0,0,0);
    }
    int eo = nt*16 + m;
    float bias = c0_b[eo];
    #pragma unroll
    for (int r=0;r<4;r++)
      hidden[(size_t)(base + kg*4 + r)*EE + eo] = acc[r] + bias;
  }
}

// ---------------- residual + RMSNorm, writes bf16 into padded conv-input ----------------
__global__ __launch_bounds__(192) void k_rms(const float* hidden, float* residual,
                                             __hip_bfloat16* __restrict__ xpad,
                                             const float* norm_w, int first){
  int row = blockIdx.x; int e = threadIdx.x;
  int o = row*EE + e;
  float h = hidden[o];
  float r = first ? h : (h + residual[o]);
  residual[o] = r;
  float s = r*r;
  #pragma unroll
  for (int m=32;m>0;m>>=1) s += __shfl_xor(s, m, 64);
  __shared__ float red[3];
  if ((e&63)==0) red[e>>6] = s;
  __syncthreads();
  float tot = red[0]+red[1]+red[2];
  float rms = rsqrtf(tot*(1.0f/EE) + 1e-5f);
  int b = row >> 12; int p = row & 4095; int y = p >> 6; int x = p & 63;
  xpad[((size_t)(b*PADW + y + PADP)*PADW + (x + PADP))*EE + e] = __float2bfloat16(r*rms*norm_w[e]);
}

// ---------------- 3x3 conv via MFMA, LDS double-buffered weights ----------------
template<int DIL, int FUSE>
__global__ __launch_bounds__(256,3) void k_conv3s(const __hip_bfloat16* __restrict__ xp,
        const __hip_bfloat16* __restrict__ wt, const float* __restrict__ bias,
        const float* __restrict__ bnw, const float* __restrict__ bnb,
        float* __restrict__ out){
  __shared__ short wlds[2][9216];
  int t = threadIdx.x;
  int lane = t & 63;
  int wv = t >> 6;
  int m = lane & 15, kg = lane >> 4;
  int rb = blockIdx.x;           // B*64 image rows
  int b = rb >> 6, y = rb & 63;
  int eoB = blockIdx.y;          // 0..3
  int x = wv*16 + m;
  const short* xs = (const short*)xp;
  const short* ws = (const short*)wt + (size_t)eoB * 82944;
  int aBase0 = ((b*PADW + y + PADP)*PADW + (x + PADP))*EE + kg*8;

  f32x4 acc0={0,0,0,0}, acc1={0,0,0,0}, acc2={0,0,0,0};

  {
    const ushort4* src = (const ushort4*)(ws);
    ushort4* dst = (ushort4*)(&wlds[0][0]);
    #pragma unroll
    for (int k=0;k<9;k++) dst[k*256+t] = src[k*256+t];
  }
  bf16x8 curA[6];
  {
    int aB = aBase0 + ((-1)*DIL*PADW + (-1)*DIL)*EE;
    #pragma unroll
    for (int e=0;e<6;e++) curA[e] = *(const bf16x8*)(xs + aB + e*32);
  }
  __syncthreads();

  for (int tap=0; tap<9; tap++){
    int cur = tap & 1;
    ushort4 nxtW[9];
    bf16x8 nxtA[6];
    if (tap < 8){
      const ushort4* src = (const ushort4*)(ws + (size_t)(tap+1)*9216);
      #pragma unroll
      for (int k=0;k<9;k++) nxtW[k] = src[k*256+t];
      int ky = (tap+1)/3, kx = (tap+1)%3;
      int aB = aBase0 + ((ky-1)*DIL*PADW + (kx-1)*DIL)*EE;
      #pragma unroll
      for (int e=0;e<6;e++) nxtA[e] = *(const bf16x8*)(xs + aB + e*32);
    }
    const short* bl = &wlds[cur][0];
    #pragma unroll
    for (int e=0;e<6;e++){
      bf16x8 b0 = *(const bf16x8*)(bl + (e*3+0)*512 + lane*8);
      bf16x8 b1 = *(const bf16x8*)(bl + (e*3+1)*512 + lane*8);
      bf16x8 b2 = *(const bf16x8*)(bl + (e*3+2)*512 + lane*8);
      acc0 = __builtin_amdgcn_mfma_f32_16x16x32_bf16(curA[e], b0, acc0, 0,0,0);
      acc1 = __builtin_amdgcn_mfma_f32_16x16x32_bf16(curA[e], b1, acc1, 0,0,0);
      acc2 = __builtin_amdgcn_mfma_f32_16x16x32_bf16(curA[e], b2, acc2, 0,0,0);
    }
    if (tap < 8){
      ushort4* dst = (ushort4*)(&wlds[cur^1][0]);
      #pragma unroll
      for (int k=0;k<9;k++) dst[k*256+t] = nxtW[k];
      #pragma unroll
      for (int e=0;e<6;e++) curA[e] = nxtA[e];
    }
    __syncthreads();
  }

  int px0 = y*64 + wv*16 + kg*4;
  #pragma unroll
  for (int nt=0; nt<3; nt++){
    f32x4 a = (nt==0)?acc0:((nt==1)?acc1:acc2);
    int eo = eoB*48 + nt*16 + m;
    float add=0.0f, scale=0.0f, sh=0.0f;
    if (FUSE){ scale = bnw[eo]*rsqrtf(1.0f+1e-5f); sh = bnb[eo]; }
    else add = bias[eo];
    #pragma unroll
    for (int r=0;r<4;r++){
      float v = a[r];
      if (FUSE) v = fmaxf(v*scale + sh, 0.0f);
      else v += add;
      out[((size_t)(b*HWp) + px0 + r)*EE + eo] = v;
    }
  }
}

// ---------------- gather easy + in-projection via split-bf16 MFMA ----------------
__global__ __launch_bounds__(256) void k_inproj(const float* __restrict__ hid, const int* easy_idx,
        const unsigned short* __restrict__ wthi, const unsigned short* __restrict__ wtlo,
        float* __restrict__ xh, float* __restrict__ zb){
  int lane = threadIdx.x & 63, wv = threadIdx.x >> 6;
  int m = lane & 15, kg = lane >> 4;
  int bid = blockIdx.x;
  int b = bid >> 5; int l0 = (bid & 31)*64 + wv*16;
  int nq = blockIdx.y;
  int row = easy_idx[b*LEc + l0 + m];
  const float* srcp = hid + (size_t)(b*HWp + row)*EE + kg*8;
  bf16x8 Ah[6], Al[6];
  #pragma unroll
  for (int ks=0; ks<6; ks++){
    const float* sp = srcp + ks*32;
    #pragma unroll
    for (int q=0;q<8;q++){
      float v = sp[q];
      unsigned short hh, ll; split_bf16(v, hh, ll);
      Ah[ks][q] = (short)hh; Al[ks][q] = (short)ll;
    }
  }
  const short* wh = (const short*)wthi;
  const short* wl = (const short*)wtlo;
  for (int ntile=0; ntile<12; ntile++){
    int nt = nq*12 + ntile;
    const short* ph = wh + (size_t)nt*3072 + lane*8;
    const short* pl = wl + (size_t)nt*3072 + lane*8;
    f32x4 acc = {0,0,0,0};
    #pragma unroll
    for (int ks=0; ks<6; ks++){
      bf16x8 Bh = *(const bf16x8*)(ph + ks*512);
      bf16x8 Bl = *(const bf16x8*)(pl + ks*512);
      acc = __builtin_amdgcn_mfma_f32_16x16x32_bf16(Ah[ks], Bh, acc, 0,0,0);
      acc = __builtin_amdgcn_mfma_f32_16x16x32_bf16(Al[ks], Bh, acc, 0,0,0);
      acc = __builtin_amdgcn_mfma_f32_16x16x32_bf16(Ah[ks], Bl, acc, 0,0,0);
      acc = __builtin_amdgcn_mfma_f32_16x16x32_bf16(Al[ks], Bl, acc, 0,0,0);
    }
    int dd = nt*16 + m;
    #pragma unroll
    for (int r=0;r<4;r++){
      int rb = b*LEc + l0 + kg*4 + r;
      float o = acc[r];
      if (dd < DIN) xh[(size_t)rb*DIN + dd] = o;
      else zb[(size_t)rb*DIN + (dd-DIN)] = o;
    }
  }
}

// ---------------- fused causal conv + dbl (wave-parallel) + dt ----------------
__global__ __launch_bounds__(128) void k_mpre(const float* xh, const float* cw, const float* cb,
                                              const float* xw, const float* dtw, const float* dtb_w,
                                              float* xc, float* bc, float* dtb){
  int row = blockIdx.x;          // B*LE
  int l = row & 2047;
  int t = threadIdx.x;
  __shared__ float sxc[DIN];
  __shared__ float spart[20][6];
  __shared__ float sdbl[20];
  for (int i=t; i<DIN; i+=128){
    const float* w = cw + i*KC;
    float s = cb[i];
    #pragma unroll
    for (int k=0;k<KC;k++){
      int ls = l - 3 + k;
      if (ls >= 0) s += w[k]*xh[(row-3+k)*DIN + i];
    }
    s = s * sigmoid_fast(s);
    sxc[i] = s;
    xc[row*DIN+i] = s;
  }
  __syncthreads();
  if (t < 120){
    int r = t / 6, u = t % 6;
    const float* w = xw + r*DIN + u*64;
    const float* sx = sxc + u*64;
    float a=0,b2=0,c=0,d2=0;
    #pragma unroll 4
    for (int i=0;i<64;i+=4){ a+=sx[i]*w[i]; b2+=sx[i+1]*w[i+1]; c+=sx[i+2]*w[i+2]; d2+=sx[i+3]*w[i+3]; }
    spart[r][u] = a+b2+c+d2;
  }
  __syncthreads();
  if (t < 20){
    float o = spart[t][0]+spart[t][1]+spart[t][2]+spart[t][3]+spart[t][4]+spart[t][5];
    sdbl[t] = o;
    if (t >= DTR) bc[row*8 + (t-DTR)] = o;
  }
  __syncthreads();
  for (int i=t; i<DIN; i+=128){
    const float* w = dtw + i*DTR;
    float s = dtb_w[i];
    #pragma unroll
    for (int k=0;k<DTR;k++) s += sdbl[k]*w[k];
    dtb[row*DIN+i] = softplus_f(s);
  }
}

// ---------------- chunked selective scan A + last-block chunk-combine ----------------
__global__ __launch_bounds__(256) void k_scanA(const float* dt, const float* xc, const float* bc,
                                               const float* Alog, float* chnk, float* hin, int* ticket){
  int g = blockIdx.x*256+threadIdx.x;    // B*NCH*DIN
  int dch = g % DIN; int c = (g/DIN) % NCH; int b = g/(DIN*NCH);
  float A[4], P[4]={1,1,1,1}, h[4]={0,0,0,0};
  #pragma unroll
  for (int n=0;n<4;n++) A[n] = -__expf(Alog[dch*DST+n]);
  int lbase = b*LEc + c*CLEN;
  for (int s=0;s<CLEN;s++){
    int base = lbase + s;
    float dtv = dt[base*DIN + dch];
    float xcv = xc[base*DIN + dch];
    float dx = dtv*xcv;
    #pragma unroll
    for (int n=0;n<4;n++){
      float dA = __expf(dtv*A[n]);
      float Bn = bc[base*8 + n];
      h[n] = dA*h[n] + dx*Bn;
      P[n] *= dA;
    }
  }
  float* o = chnk + (size_t)g*8;
  #pragma unroll
  for (int n=0;n<4;n++){ o[n]=P[n]; o[4+n]=h[n]; }
  __threadfence();
  __syncthreads();
  __shared__ int amlast;
  if (threadIdx.x == 0)
    amlast = (atomicAdd(ticket, 1) == (int)gridDim.x - 1) ? 1 : 0;
  __syncthreads();
  if (!amlast) return;
  __threadfence();
  // chunk combine (former k_scanB), 768 tasks on 256 threads
  for (int g2 = threadIdx.x; g2 < BB*DIN; g2 += 256){
    int dch2 = g2 % DIN; int b2 = g2 / DIN;
    float h0=0,h1=0,h2=0,h3=0;
    for (int cb2=0; cb2<NCH/8; cb2++){
      float4 P2[8], Hl[8];
      #pragma unroll
      for (int u=0;u<8;u++){
        const float4* cp = (const float4*)(chnk + (size_t)((b2*NCH + cb2*8+u)*DIN + dch2)*8);
        P2[u] = cp[0]; Hl[u] = cp[1];
      }
      #pragma unroll
      for (int u=0;u<8;u++){
        int idx = (b2*NCH + cb2*8+u)*DIN + dch2;
        float4 hv; hv.x=h0; hv.y=h1; hv.z=h2; hv.w=h3;
        *(float4*)(hin + (size_t)idx*4) = hv;
        h0 = P2[u].x*h0 + Hl[u].x;
        h1 = P2[u].y*h1 + Hl[u].y;
        h2 = P2[u].z*h2 + Hl[u].z;
        h3 = P2[u].w*h3 + Hl[u].w;
      }
    }
  }
}

__global__ void k_scanC(const float* dt, const float* xc, const float* zb, const float* bc, const float* Alog,
                        const float* Dw, const float* hin, float* yb){
  int g = blockIdx.x*256+threadIdx.x;    // B*NCH*DIN
  int dch = g % DIN; int c = (g/DIN) % NCH; int b = g/(DIN*NCH);
  float A[4], h[4];
  #pragma unroll
  for (int n=0;n<4;n++){ A[n] = -__expf(Alog[dch*DST+n]); h[n] = hin[(size_t)g*4+n]; }
  float Dv = Dw[dch];
  int lbase = b*LEc + c*CLEN;
  for (int s=0;s<CLEN;s++){
    int base = lbase + s;
    float dtv = dt[base*DIN+dch];
    float xcv = xc[base*DIN+dch];
    float zv  = zb[base*DIN+dch];
    float dx = dtv*xcv;
    float y = 0.0f;
    #pragma unroll
    for (int n=0;n<4;n++){
      float dA = __expf(dtv*A[n]);
      h[n] = dA*h[n] + dx*bc[base*8+n];
      y += h[n]*bc[base*8+4+n];
    }
    y = (y + Dv*xcv) * (zv * sigmoid_fast(zv));
    yb[base*DIN + dch] = y;
  }
}

// ---------------- out-projection via split-bf16 MFMA + scatter ----------------
__global__ __launch_bounds__(256) void k_outproj(const float* __restrict__ yb, const int* easy_idx,
        const unsigned short* __restrict__ wthi, const unsigned short* __restrict__ wtlo,
        float* __restrict__ hidden){
  int lane = threadIdx.x & 63, wv = threadIdx.x >> 6;
  int m = lane & 15, kg = lane >> 4;
  int bid = blockIdx.x;
  int b = bid >> 5; int l0 = (bid & 31)*64 + wv*16;
  int nq = blockIdx.y;
  const float* srcp = yb + (size_t)(b*LEc + l0 + m)*DIN + kg*8;
  bf16x8 Ah[12], Al[12];
  #pragma unroll
  for (int ks=0; ks<12; ks++){
    const float* sp = srcp + ks*32;
    #pragma unroll
    for (int q=0;q<8;q++){
      unsigned short hh, ll; split_bf16(sp[q], hh, ll);
      Ah[ks][q] = (short)hh; Al[ks][q] = (short)ll;
    }
  }
  int rows[4];
  #pragma unroll
  for (int r=0;r<4;r++) rows[r] = easy_idx[b*LEc + l0 + kg*4 + r];
  const short* wh = (const short*)wthi;
  const short* wl = (const short*)wtlo;
  for (int ntile=0; ntile<3; ntile++){
    int nt = nq*3 + ntile;
    const short* ph = wh + (size_t)nt*6144 + lane*8;
    const short* pl = wl + (size_t)nt*6144 + lane*8;
    f32x4 acc = {0,0,0,0};
    #pragma unroll
    for (int ks=0; ks<12; ks++){
      bf16x8 Bh = *(const bf16x8*)(ph + ks*512);
      bf16x8 Bl = *(const bf16x8*)(pl + ks*512);
      acc = __builtin_amdgcn_mfma_f32_16x16x32_bf16(Ah[ks], Bh, acc, 0,0,0);
      acc = __builtin_amdgcn_mfma_f32_16x16x32_bf16(Al[ks], Bh, acc, 0,0,0);
      acc = __builtin_amdgcn_mfma_f32_16x16x32_bf16(Ah[ks], Bl, acc, 0,0,0);
      acc = __builtin_amdgcn_mfma_f32_16x16x32_bf16(Al[ks], Bl, acc, 0,0,0);
    }
    int eo = nt*16 + m;
    #pragma unroll
    for (int r=0;r<4;r++)
      hidden[(size_t)(b*HWp + rows[r])*EE + eo] = acc[r];
  }
}

// ---------------- final LayerNorm -> bf16 padded conv-input ----------------
__global__ __launch_bounds__(192) void k_ln(const float* hidden, const float* residual,
                                            const float* lnw, const float* lnb,
                                            __hip_bfloat16* __restrict__ xpad){
  int row = blockIdx.x; int e = threadIdx.x;
  int o = row*EE + e;
  float v = hidden[o] + residual[o];
  __shared__ float redA[3], redB[3];
  float s = v;
  #pragma unroll
  for (int m=32;m>0;m>>=1) s += __shfl_xor(s, m, 64);
  if ((e&63)==0) redA[e>>6] = s;
  __syncthreads();
  float mu = (redA[0]+redA[1]+redA[2])*(1.0f/EE);
  float dv = v - mu;
  float s2 = dv*dv;
  #pragma unroll
  for (int m=32;m>0;m>>=1) s2 += __shfl_xor(s2, m, 64);
  if ((e&63)==0) redB[e>>6] = s2;
  __syncthreads();
  float var = (redB[0]+redB[1]+redB[2])*(1.0f/EE);
  float o2 = dv*rsqrtf(var + 1e-5f)*lnw[e] + lnb[e];
  int b = row >> 12; int p = row & 4095; int y = p >> 6; int x = p & 63;
  xpad[((size_t)(b*PADW + y + PADP)*PADW + (x + PADP))*EE + e] = __float2bfloat16(o2);
}

// ---------------- classifier 1x1 (192 -> 9) ----------------
__global__ __launch_bounds__(64) void k_cls(const float* h1, const float* cls_w, const float* cls_b, float* out){
  __shared__ float wsm[NCc][EE];
  int t = threadIdx.x;
  for (int i=t; i<NCc*EE; i+=64){ wsm[i/EE][i%EE] = cls_w[i]; }
  __syncthreads();
  int g = blockIdx.x*64 + t;           // B*HW, grid 128
  int p = g & 4095; int b = g >> 12;
  const float4* hrow = (const float4*)(h1 + (size_t)g*EE);
  float acc[NCc];
  #pragma unroll
  for (int n=0;n<NCc;n++) acc[n] = cls_b[n];
  for (int c4=0;c4<EE/4;c4++){
    float4 h = hrow[c4];
    #pragma unroll
    for (int n=0;n<NCc;n++){
      const float4 wv = *(const float4*)(&wsm[n][c4*4]);
      acc[n] += h.x*wv.x + h.y*wv.y + h.z*wv.z + h.w*wv.w;
    }
  }
  #pragma unroll
  for (int n=0;n<NCc;n++)
    out[((size_t)b*NCc + n)*HWp + p] = acc[n];
}

// ================= host launch =================
extern "C" void kernel_launch(void* const* d_in, const int* in_sizes, int n_in,
                              void* d_out, int out_size, void* d_ws, size_t ws_size,
                              hipStream_t stream) {
  const float* x          = (const float*)d_in[0];
  const float* sp_w       = (const float*)d_in[2];
  const float* sp_b       = (const float*)d_in[3];
  const float* c0_w       = (const float*)d_in[4];
  const float* c0_b       = (const float*)d_in[5];
  const float* blk_norm_w = (const float*)d_in[6];
  const float* blk_conv_w = (const float*)d_in[7];
  const float* blk_conv_b = (const float*)d_in[8];
  const float* m_in_w     = (const float*)d_in[9];
  const float* m_conv_w   = (const float*)d_in[10];
  const float* m_conv_b   = (const float*)d_in[11];
  const float* m_x_w      = (const float*)d_in[12];
  const float* m_dt_w     = (const float*)d_in[13];
  const float* m_dt_b     = (const float*)d_in[14];
  const float* m_Alog     = (const float*)d_in[15];
  const float* m_D        = (const float*)d_in[16];
  const float* m_out_w    = (const float*)d_in[17];
  const float* ln_w       = (const float*)d_in[18];
  const float* ln_b       = (const float*)d_in[19];
  const float* h_conv_w   = (const float*)d_in[20];
  const float* h_bn_w     = (const float*)d_in[21];
  const float* h_bn_b     = (const float*)d_in[22];
  const float* h_cls_w    = (const float*)d_in[23];
  const float* h_cls_b    = (const float*)d_in[24];

  float* out_sp     = (float*)d_out;          // B*HW
  float* out_logits = (float*)d_out + BB*HWp; // B*NC*HW

  // workspace carve-up (floats)
  float* w = (float*)d_ws;
  size_t off = 0;
  auto alloc = [&](size_t n){ float* p = w + off; off += (n + 63) & ~size_t(63); return p; };
  float* res2    = alloc(BB*HWp*CH);
  float* feats   = alloc(BB*HWp*CH);
  float* scores  = alloc(BB*HWp);
  float* bnorm   = alloc(BB*SAMPLE);
  float* hidden  = alloc(BB*HWp*EE);
  float* residual= alloc(BB*HWp*EE);
  float* hid2    = alloc(BB*HWp*EE);
  float* xh      = alloc(BB*LEc*DIN);
  float* zb      = alloc(BB*LEc*DIN);
  float* xc      = alloc(BB*LEc*DIN);
  float* dtb     = alloc(BB*LEc*DIN);
  float* yb      = alloc(BB*LEc*DIN);
  float* bcbuf   = alloc(BB*LEc*8);
  float* pval    = alloc(BB*HWp*NSPLIT);
  float* chnk    = alloc((size_t)BB*NCH*DIN*8);
  float* hin     = alloc((size_t)BB*NCH*DIN*4);
  __hip_bfloat16* wtb_blk  = (__hip_bfloat16*)alloc(SZ_WTBLK_BF/2);
  __hip_bfloat16* wtb_head = (__hip_bfloat16*)alloc(SZ_WTHEAD_BF/2);
  unsigned short* wtb_in_hi = (unsigned short*)alloc(SZ_WTIN/2);
  unsigned short* wtb_in_lo = (unsigned short*)alloc(SZ_WTIN/2);
  unsigned short* wtb_out_hi = (unsigned short*)alloc(SZ_WTOUT/2);
  unsigned short* wtb_out_lo = (unsigned short*)alloc(SZ_WTOUT/2);
  unsigned short* wtc0_hi = (unsigned short*)alloc(SZ_WTC0/2);
  unsigned short* wtc0_lo = (unsigned short*)alloc(SZ_WTC0/2);
  __hip_bfloat16* xpad     = (__hip_bfloat16*)alloc(BB*PADW*PADW*EE/2);
  unsigned short* fhi    = (unsigned short*)alloc(BB*HWp*CH/2);
  unsigned short* flo    = (unsigned short*)alloc(BB*HWp*CH/2);
  unsigned short* bankhi = (unsigned short*)alloc(BB*SAMPLE*CH/2);
  unsigned short* banklo = (unsigned short*)alloc(BB*SAMPLE*CH/2);
  int* pidx       = (int*)alloc(BB*HWp*NSPLIT);
  int* idx_sorted = (int*)alloc(BB*SAMPLE);
  int* ranks      = (int*)alloc(BB*HWp);
  int* easy_idx   = (int*)alloc(BB*LEc);
  int* tickets    = (int*)alloc(NTICK);
  if (off*sizeof(float) > ws_size) return;  // workspace too small -> fail loud via validation

  prep_weights<<<(SZ_WT_TOTAL+NXPI+NRANKS+NTICK+255)/256, 256, 0, stream>>>(
      blk_conv_w, h_conv_w, m_in_w, m_out_w, c0_w,
      wtb_blk, wtb_head, wtb_in_hi, wtb_in_lo, wtb_out_hi, wtb_out_lo,
      wtc0_hi, wtc0_lo, (int*)xpad, ranks, tickets);
  k_prep2<<<BB*HWp/32, 256, 0, stream>>>(x, sp_w, sp_b, res2, feats, fhi, flo, scores, out_sp);
  k_rank2<<<dim3(16,16,BB), 256, 0, stream>>>(scores, ranks, tickets+0, idx_sorted, easy_idx);
  k_bank<<<BB*SAMPLE/64, 64, 0, stream>>>(feats, idx_sorted, bnorm, bankhi, banklo);
  k_nn_mfma<<<dim3(HWp/64, NSPLIT, BB), 256, 0, stream>>>(fhi, flo, bankhi, banklo, bnorm,
                                                          idx_sorted, pval, pidx);
  k_c0<<<dim3(BB*HWp/64, 4), 256, 0, stream>>>(res2, feats, idx_sorted, pval, pidx,
                                               wtc0_hi, wtc0_lo, c0_b, hidden);

  for (int d=0; d<2; d++){
    k_rms<<<BB*HWp, 192, 0, stream>>>(hidden, residual, xpad, blk_norm_w + d*EE, d==0);
    k_conv3s<1,0><<<dim3(BB*64,4), 256, 0, stream>>>(xpad, wtb_blk + d*9*EE*EE,
                                                     blk_conv_b + d*EE, nullptr, nullptr, hidden);
    k_inproj<<<dim3(BB*LEc/64, 4), 256, 0, stream>>>(hidden, easy_idx,
                                                     wtb_in_hi + (size_t)d*147456,
                                                     wtb_in_lo + (size_t)d*147456, xh, zb);
    k_mpre<<<BB*LEc, 128, 0, stream>>>(xh, m_conv_w + d*DIN*KC, m_conv_b + d*DIN,
                                       m_x_w + d*(DTR+2*DST)*DIN, m_dt_w + d*DIN*DTR, m_dt_b + d*DIN,
                                       xc, bcbuf, dtb);
    k_scanA<<<BB*NCH*DIN/256, 256, 0, stream>>>(dtb, xc, bcbuf, m_Alog + d*DIN*DST,
                                                chnk, hin, tickets+1+d);
    k_scanC<<<BB*NCH*DIN/256, 256, 0, stream>>>(dtb, xc, zb, bcbuf, m_Alog + d*DIN*DST,
                                                m_D + d*DIN, hin, yb);
    k_outproj<<<dim3(BB*LEc/64, 4), 256, 0, stream>>>(yb, easy_idx,
                                                      wtb_out_hi + (size_t)d*73728,
                                                      wtb_out_lo + (size_t)d*73728, hidden);
  }

  k_ln<<<BB*HWp, 192, 0, stream>>>(hidden, residual, ln_w, ln_b, xpad);
  k_conv3s<3,1><<<dim3(BB*64,4), 256, 0, stream>>>(xpad, wtb_head, nullptr, h_bn_w, h_bn_b, hid2);
  k_cls<<<BB*HWp/64, 64, 0, stream>>>(hid2, h_cls_w, h_cls_b, out_logits);
}

// Round 19
// 357.867 us; speedup vs baseline: 1.5315x; 1.5315x over previous
//
#include <hip/hip_runtime.h>
#include <hip/hip_bf16.h>
#include <math.h>

#define BB 2
#define HWp 4096
#define CH 64
#define CIN 128
#define EE 192
#define DIN 384
#define DST 4
#define DTR 12
#define KC 4
#define NCc 9
#define SAMPLE 2048
#define LEc 2048
#define NCH 128
#define CLEN 16
#define NSPLIT 8
#define PADW 70
#define PADP 3

typedef __attribute__((ext_vector_type(8))) short bf16x8;
typedef __attribute__((ext_vector_type(4))) float f32x4;

__device__ __forceinline__ float sigmoid_fast(float x){ return 1.0f/(1.0f+__expf(-x)); }
__device__ __forceinline__ float softplus_f(float x){ return fmaxf(x,0.0f) + log1pf(expf(-fabsf(x))); }

__device__ __forceinline__ void split_bf16(float v, unsigned short& h, unsigned short& l){
  __hip_bfloat16 bh = __float2bfloat16(v);
  h = *(unsigned short*)&bh;
  float r = v - __bfloat162float(bh);
  __hip_bfloat16 bl = __float2bfloat16(r);
  l = *(unsigned short*)&bl;
}

// ---------------- weight prep + zero fills ----------------
#define SZ_WTBLK_BF (2*9*EE*EE)
#define SZ_WTHEAD_BF (9*EE*EE)
#define SZ_WTIN (2*EE*2*DIN)
#define SZ_WTOUT (2*DIN*EE)
#define SZ_WTC0 (CIN*EE)
#define SZ_WT_TOTAL (SZ_WTBLK_BF+SZ_WTHEAD_BF+SZ_WTIN+SZ_WTOUT+SZ_WTC0)
#define NXPI (BB*PADW*PADW*EE/2)
#define NRANKS (BB*HWp)

__global__ void prep_weights(const float* blk_w, const float* head_w, const float* in_w,
                             const float* out_w, const float* c0_w,
                             __hip_bfloat16* wtb_blk, __hip_bfloat16* wtb_head,
                             unsigned short* wtb_in_hi, unsigned short* wtb_in_lo,
                             unsigned short* wtb_out_hi, unsigned short* wtb_out_lo,
                             unsigned short* wtc0_hi, unsigned short* wtc0_lo,
                             int* xpad_i, int* ranks){
  int i = blockIdx.x*256 + threadIdx.x;
  if (i >= SZ_WT_TOTAL + NXPI + NRANKS) return;
  int o = i;
  if (o < SZ_WTBLK_BF){
    int j = o & 7;
    int lane = (o>>3) & 63;
    int nt = (o/512) % 3;
    int e = (o/1536) % 6;
    int tap = (o/9216) % 9;
    int eoB = (o/82944) % 4;
    int d = o / 331776;
    int m = lane & 15, kg = lane >> 4;
    int eo = eoB*48 + nt*16 + m;
    int ei = e*32 + kg*8 + j;
    wtb_blk[o] = __float2bfloat16(blk_w[(((d*EE+eo)*EE+ei)*9)+tap]);
    return;
  }
  o -= SZ_WTBLK_BF;
  if (o < SZ_WTHEAD_BF){
    int j = o & 7;
    int lane = (o>>3) & 63;
    int nt = (o/512) % 3;
    int e = (o/1536) % 6;
    int tap = (o/9216) % 9;
    int eoB = (o/82944) % 4;
    int m = lane & 15, kg = lane >> 4;
    int eo = eoB*48 + nt*16 + m;
    int ei = e*32 + kg*8 + j;
    wtb_head[o] = __float2bfloat16(head_w[((eo*EE+ei)*9)+tap]);
    return;
  }
  o -= SZ_WTHEAD_BF;
  if (o < SZ_WTIN){
    int j = o & 7;
    int lane = (o>>3) & 63;
    int ks = (o/512) % 6;
    int nt = (o/3072) % 48;
    int d = o / 147456;
    int m = lane & 15, kg = lane >> 4;
    int dd = nt*16 + m;
    int ei = ks*32 + kg*8 + j;
    float v = in_w[((size_t)(d*768)+dd)*EE + ei];
    unsigned short hh, ll; split_bf16(v, hh, ll);
    wtb_in_hi[o] = hh; wtb_in_lo[o] = ll;
    return;
  }
  o -= SZ_WTIN;
  if (o < SZ_WTOUT){
    int j = o & 7;
    int lane = (o>>3) & 63;
    int ks = (o/512) % 12;
    int nt = (o/6144) % 12;
    int d = o / 73728;
    int m = lane & 15, kg = lane >> 4;
    int eo = nt*16 + m;
    int dch = ks*32 + kg*8 + j;
    float v = out_w[((size_t)(d*EE)+eo)*DIN + dch];
    unsigned short hh, ll; split_bf16(v, hh, ll);
    wtb_out_hi[o] = hh; wtb_out_lo[o] = ll;
    return;
  }
  o -= SZ_WTOUT;
  if (o < SZ_WTC0){
    int j = o & 7;
    int lane = (o>>3) & 63;
    int ks = (o/512) % 4;
    int nt = o / 2048;
    int m = lane & 15, kg = lane >> 4;
    int e = nt*16 + m;
    int c = ks*32 + kg*8 + j;
    float v = c0_w[e*CIN + c];
    unsigned short hh, ll; split_bf16(v, hh, ll);
    wtc0_hi[o] = hh; wtc0_lo[o] = ll;
    return;
  }
  o -= SZ_WTC0;
  if (o < NXPI){ xpad_i[o] = 0; return; }
  o -= NXPI;
  ranks[o] = 0;
}

// ---------------- stage 1: res^2, feats(+bf16 hi/lo), simple_pred, scores ----------------
__global__ __launch_bounds__(256) void k_prep2(const float* __restrict__ x, const float* sp_w,
                       const float* sp_b, float* __restrict__ res2, float* __restrict__ feats,
                       unsigned short* __restrict__ fhi, unsigned short* __restrict__ flo,
                       float* scores, float* outSP){
  __shared__ float tile[CIN][33];
  int t = threadIdx.x;
  int p0 = blockIdx.x * 32;             // grid BB*HWp/32 = 256 blocks
  int b = p0 >> 12; int prow = p0 & 4095;
  const float* xb = x + (size_t)b*CIN*HWp + prow;
  #pragma unroll
  for (int i=0;i<4;i++){
    int idx = i*256 + t;
    int c = idx >> 3;            // 0..127
    int p4 = idx & 7;            // 8 float4 per row
    float4 v = *(const float4*)(xb + (size_t)c*HWp + p4*4);
    tile[c][p4*4+0]=v.x; tile[c][p4*4+1]=v.y; tile[c][p4*4+2]=v.z; tile[c][p4*4+3]=v.w;
  }
  __syncthreads();
  int lane = t & 63;
  int wv = t >> 6;
  float sw = sp_w[lane];
  float sb = sp_b[0];
  #pragma unroll
  for (int k=0;k<8;k++){
    int p = wv*8 + k;
    float v = tile[lane][p];
    float r2 = v*v;
    float f = tile[64+lane][p];
    int g = p0 + p;
    res2[(size_t)g*CH + lane] = r2;
    feats[(size_t)g*CH + lane] = f;
    unsigned short hh, ll;
    split_bf16(f, hh, ll);
    fhi[(size_t)g*CH + lane] = hh;
    flo[(size_t)g*CH + lane] = ll;
    float aS = r2*sw, aM = r2;
    #pragma unroll
    for (int msk=32; msk>0; msk>>=1){
      aS += __shfl_xor(aS, msk, 64);
      aM += __shfl_xor(aM, msk, 64);
    }
    if (lane == 0){
      float sp = 1.0f/(1.0f+expf(-(aS + sb)));
      outSP[g] = sp;
      scores[g] = sp + aM*(1.0f/CH);
    }
  }
}

// ---------------- stable-argsort via ranks (2D partial + atomics) ----------------
__global__ void k_rank2(const float* scores, int* ranks){
  int b = blockIdx.z;
  int t = threadIdx.x;
  int p = blockIdx.x*256 + t;
  int j0 = blockIdx.y*256;
  __shared__ float s[256];
  s[t] = scores[b*HWp + j0 + t];
  float sp = scores[b*HWp + p];
  __syncthreads();
  int r = 0;
  #pragma unroll 8
  for (int jj=0;jj<256;jj++){
    float sj = s[jj];
    int j = j0 + jj;
    r += (sj < sp || (sj == sp && j < p)) ? 1 : 0;
  }
  atomicAdd(&ranks[b*HWp+p], r);
}

// ---------------- idx_sorted + easy_idx (wave-shuffle scan) ----------------
__global__ __launch_bounds__(1024) void k_easy(const int* ranks, int* idx_sorted, int* easy_idx){
  int b = blockIdx.x; int t = threadIdx.x;
  int lane = t & 63, wv = t >> 6;
  int i0 = t*4;
  int r0 = ranks[b*HWp+i0];
  int r1 = ranks[b*HWp+i0+1];
  int r2 = ranks[b*HWp+i0+2];
  int r3 = ranks[b*HWp+i0+3];
  int f0 = r0 >= SAMPLE, f1 = r1 >= SAMPLE, f2 = r2 >= SAMPLE, f3 = r3 >= SAMPLE;
  if (!f0) idx_sorted[b*SAMPLE + r0] = i0;
  if (!f1) idx_sorted[b*SAMPLE + r1] = i0+1;
  if (!f2) idx_sorted[b*SAMPLE + r2] = i0+2;
  if (!f3) idx_sorted[b*SAMPLE + r3] = i0+3;
  int cnt = f0+f1+f2+f3;
  int inc = cnt;
  #pragma unroll
  for (int off=1; off<64; off<<=1){
    int v = __shfl_up(inc, off, 64);
    if (lane >= off) inc += v;
  }
  __shared__ int wsum[16], woff[16];
  if (lane == 63) wsum[wv] = inc;
  __syncthreads();
  if (t == 0){
    int acc = 0;
    #pragma unroll
    for (int i=0;i<16;i++){ woff[i] = acc; acc += wsum[i]; }
  }
  __syncthreads();
  int pre = woff[wv] + inc - cnt;
  int base = b*LEc;
  if (f0) easy_idx[base+pre++] = i0;
  if (f1) easy_idx[base+pre++] = i0+1;
  if (f2) easy_idx[base+pre++] = i0+2;
  if (f3) easy_idx[base+pre]   = i0+3;
}

// ---------------- bank: norms + gathered bf16 hi/lo rows ----------------
__global__ __launch_bounds__(64) void k_bank(const float* __restrict__ feats, const int* __restrict__ idx_sorted,
                       float* __restrict__ bnorm, unsigned short* __restrict__ bankhi,
                       unsigned short* __restrict__ banklo){
  int t = blockIdx.x*64+threadIdx.x;  // B*SAMPLE, grid 64
  int b = t>>11;
  int row = idx_sorted[t];
  const float4* fr = (const float4*)(feats + (size_t)(b*HWp + row)*CH);
  ushort4* oh = (ushort4*)(bankhi + (size_t)t*CH);
  ushort4* ol = (ushort4*)(banklo + (size_t)t*CH);
  float s=0;
  #pragma unroll
  for (int k=0;k<16;k++){
    float4 v = fr[k];
    s += v.x*v.x+v.y*v.y+v.z*v.z+v.w*v.w;
    ushort4 h, l;
    split_bf16(v.x, h.x, l.x);
    split_bf16(v.y, h.y, l.y);
    split_bf16(v.z, h.z, l.z);
    split_bf16(v.w, h.w, l.w);
    oh[k] = h; ol[k] = l;
  }
  bnorm[t] = s;
}

// ---------------- NN search via split-bf16 MFMA ----------------
__global__ __launch_bounds__(256) void k_nn_mfma(const unsigned short* __restrict__ fhi,
        const unsigned short* __restrict__ flo, const unsigned short* __restrict__ bankhi,
        const unsigned short* __restrict__ banklo, const float* __restrict__ bnorm,
        const int* __restrict__ idx_sorted, float* __restrict__ pval, int* __restrict__ pidx){
  int lane = threadIdx.x & 63;
  int wv = threadIdx.x >> 6;
  int m = lane & 15, kg = lane >> 4;
  int b = blockIdx.z;
  int qrel0 = blockIdx.x*64 + wv*16;
  int jsplit = blockIdx.y;
  const short* qh = (const short*)fhi + ((size_t)(b*HWp + qrel0 + m))*CH + kg*8;
  const short* ql = (const short*)flo + ((size_t)(b*HWp + qrel0 + m))*CH + kg*8;
  bf16x8 Ah0 = *(const bf16x8*)(qh);
  bf16x8 Ah1 = *(const bf16x8*)(qh + 32);
  bf16x8 Al0 = *(const bf16x8*)(ql);
  bf16x8 Al1 = *(const bf16x8*)(ql + 32);
  float best0=1e30f,best1=1e30f,best2=1e30f,best3=1e30f;
  int bj0=0,bj1=0,bj2=0,bj3=0;
  for (int jt=0; jt<16; jt++){
    int jb = jsplit*256 + jt*16;
    int j = jb + m;
    const short* bh = (const short*)bankhi + ((size_t)(b*SAMPLE + j))*CH + kg*8;
    const short* bl = (const short*)banklo + ((size_t)(b*SAMPLE + j))*CH + kg*8;
    bf16x8 Bh0 = *(const bf16x8*)(bh);
    bf16x8 Bh1 = *(const bf16x8*)(bh + 32);
    bf16x8 Bl0 = *(const bf16x8*)(bl);
    bf16x8 Bl1 = *(const bf16x8*)(bl + 32);
    f32x4 acc = {0,0,0,0};
    acc = __builtin_amdgcn_mfma_f32_16x16x32_bf16(Ah0, Bh0, acc, 0,0,0);
    acc = __builtin_amdgcn_mfma_f32_16x16x32_bf16(Ah1, Bh1, acc, 0,0,0);
    acc = __builtin_amdgcn_mfma_f32_16x16x32_bf16(Al0, Bh0, acc, 0,0,0);
    acc = __builtin_amdgcn_mfma_f32_16x16x32_bf16(Al1, Bh1, acc, 0,0,0);
    acc = __builtin_amdgcn_mfma_f32_16x16x32_bf16(Ah0, Bl0, acc, 0,0,0);
    acc = __builtin_amdgcn_mfma_f32_16x16x32_bf16(Ah1, Bl1, acc, 0,0,0);
    acc = __builtin_amdgcn_mfma_f32_16x16x32_bf16(Al0, Bl0, acc, 0,0,0);
    acc = __builtin_amdgcn_mfma_f32_16x16x32_bf16(Al1, Bl1, acc, 0,0,0);
    float bn = bnorm[b*SAMPLE + j];
    int src = idx_sorted[b*SAMPLE + j];
    float v0 = bn - 2.0f*acc[0];
    float v1 = bn - 2.0f*acc[1];
    float v2 = bn - 2.0f*acc[2];
    float v3 = bn - 2.0f*acc[3];
    int qp = qrel0 + kg*4;
    if (src != qp   && v0 < best0){ best0 = v0; bj0 = j; }
    if (src != qp+1 && v1 < best1){ best1 = v1; bj1 = j; }
    if (src != qp+2 && v2 < best2){ best2 = v2; bj2 = j; }
    if (src != qp+3 && v3 < best3){ best3 = v3; bj3 = j; }
  }
  #pragma unroll
  for (int mask=1; mask<16; mask<<=1){
    float ov; int oj;
    ov = __shfl_xor(best0, mask, 64); oj = __shfl_xor(bj0, mask, 64);
    if (ov < best0 || (ov == best0 && oj < bj0)){ best0 = ov; bj0 = oj; }
    ov = __shfl_xor(best1, mask, 64); oj = __shfl_xor(bj1, mask, 64);
    if (ov < best1 || (ov == best1 && oj < bj1)){ best1 = ov; bj1 = oj; }
    ov = __shfl_xor(best2, mask, 64); oj = __shfl_xor(bj2, mask, 64);
    if (ov < best2 || (ov == best2 && oj < bj2)){ best2 = ov; bj2 = oj; }
    ov = __shfl_xor(best3, mask, 64); oj = __shfl_xor(bj3, mask, 64);
    if (ov < best3 || (ov == best3 && oj < bj3)){ best3 = ov; bj3 = oj; }
  }
  if (m == 0){
    int qg = b*HWp + qrel0 + kg*4;
    pval[(qg+0)*NSPLIT + jsplit] = best0; pidx[(qg+0)*NSPLIT + jsplit] = bj0;
    pval[(qg+1)*NSPLIT + jsplit] = best1; pidx[(qg+1)*NSPLIT + jsplit] = bj1;
    pval[(qg+2)*NSPLIT + jsplit] = best2; pidx[(qg+2)*NSPLIT + jsplit] = bj2;
    pval[(qg+3)*NSPLIT + jsplit] = best3; pidx[(qg+3)*NSPLIT + jsplit] = bj3;
  }
}

// ---------------- 1x1 conv c0 via split-bf16 MFMA + fused NN resolve ----------------
__global__ __launch_bounds__(256) void k_c0(const float* __restrict__ res2, const float* __restrict__ feats,
        const int* idx_sorted, const float* pval, const int* pidx,
        const unsigned short* __restrict__ wthi, const unsigned short* __restrict__ wtlo,
        const float* c0_b, float* __restrict__ hidden){
  int lane = threadIdx.x & 63, wv = threadIdx.x >> 6;
  int m = lane & 15, kg = lane >> 4;
  int base = blockIdx.x*64 + wv*16;    // grid.x = BB*HWp/64 = 128
  int b = base >> 12;
  int nq = blockIdx.y;
  int px = base + m;
  float best = 1e30f; int bj = 0;
  #pragma unroll
  for (int s=0;s<NSPLIT;s++){
    float v = pval[px*NSPLIT+s]; int j = pidx[px*NSPLIT+s];
    if (v < best){ best = v; bj = j; }
  }
  int brow = idx_sorted[b*SAMPLE + bj];
  bf16x8 Ah[4], Al[4];
  #pragma unroll
  for (int ks=0; ks<4; ks++){
    int k0 = ks*32 + kg*8;
    #pragma unroll
    for (int q=0;q<8;q++){
      int k = k0 + q;
      float v;
      if (k < CH) v = res2[(size_t)px*CH + k];
      else {
        int cc = k - CH;
        float a = feats[(size_t)(b*HWp + brow)*CH + cc];
        float f = feats[(size_t)px*CH + cc];
        float d = a - f; v = d*d;
      }
      unsigned short hh, ll; split_bf16(v, hh, ll);
      Ah[ks][q] = (short)hh; Al[ks][q] = (short)ll;
    }
  }
  const short* wh = (const short*)wthi;
  const short* wl = (const short*)wtlo;
  for (int ntile=0; ntile<3; ntile++){
    int nt = nq*3 + ntile;
    const short* ph = wh + (size_t)nt*2048 + lane*8;
    const short* pl = wl + (size_t)nt*2048 + lane*8;
    f32x4 acc = {0,0,0,0};
    #pragma unroll
    for (int ks=0; ks<4; ks++){
      bf16x8 Bh = *(const bf16x8*)(ph + ks*512);
      bf16x8 Bl = *(const bf16x8*)(pl + ks*512);
      acc = __builtin_amdgcn_mfma_f32_16x16x32_bf16(Ah[ks], Bh, acc, 0,0,0);
      acc = __builtin_amdgcn_mfma_f32_16x16x32_bf16(Al[ks], Bh, acc, 0,0,0);
      acc = __builtin_amdgcn_mfma_f32_16x16x32_bf16(Ah[ks], Bl, acc, 0,0,0);
      acc = __builtin_amdgcn_mfma_f32_16x16x32_bf16(Al[ks], Bl, acc, 0,0,0);
    }
    int eo = nt*16 + m;
    float bias = c0_b[eo];
    #pragma unroll
    for (int r=0;r<4;r++)
      hidden[(size_t)(base + kg*4 + r)*EE + eo] = acc[r] + bias;
  }
}

// ---------------- residual + RMSNorm, writes bf16 into padded conv-input ----------------
__global__ __launch_bounds__(192) void k_rms(const float* hidden, float* residual,
                                             __hip_bfloat16* __restrict__ xpad,
                                             const float* norm_w, int first){
  int row = blockIdx.x; int e = threadIdx.x;
  int o = row*EE + e;
  float h = hidden[o];
  float r = first ? h : (h + residual[o]);
  residual[o] = r;
  float s = r*r;
  #pragma unroll
  for (int m=32;m>0;m>>=1) s += __shfl_xor(s, m, 64);
  __shared__ float red[3];
  if ((e&63)==0) red[e>>6] = s;
  __syncthreads();
  float tot = red[0]+red[1]+red[2];
  float rms = rsqrtf(tot*(1.0f/EE) + 1e-5f);
  int b = row >> 12; int p = row & 4095; int y = p >> 6; int x = p & 63;
  xpad[((size_t)(b*PADW + y + PADP)*PADW + (x + PADP))*EE + e] = __float2bfloat16(r*rms*norm_w[e]);
}

// ---------------- 3x3 conv via MFMA, LDS double-buffered weights ----------------
template<int DIL, int FUSE>
__global__ __launch_bounds__(256,3) void k_conv3s(const __hip_bfloat16* __restrict__ xp,
        const __hip_bfloat16* __restrict__ wt, const float* __restrict__ bias,
        const float* __restrict__ bnw, const float* __restrict__ bnb,
        float* __restrict__ out){
  __shared__ short wlds[2][9216];
  int t = threadIdx.x;
  int lane = t & 63;
  int wv = t >> 6;
  int m = lane & 15, kg = lane >> 4;
  int rb = blockIdx.x;           // B*64 image rows
  int b = rb >> 6, y = rb & 63;
  int eoB = blockIdx.y;          // 0..3
  int x = wv*16 + m;
  const short* xs = (const short*)xp;
  const short* ws = (const short*)wt + (size_t)eoB * 82944;
  int aBase0 = ((b*PADW + y + PADP)*PADW + (x + PADP))*EE + kg*8;

  f32x4 acc0={0,0,0,0}, acc1={0,0,0,0}, acc2={0,0,0,0};

  {
    const ushort4* src = (const ushort4*)(ws);
    ushort4* dst = (ushort4*)(&wlds[0][0]);
    #pragma unroll
    for (int k=0;k<9;k++) dst[k*256+t] = src[k*256+t];
  }
  bf16x8 curA[6];
  {
    int aB = aBase0 + ((-1)*DIL*PADW + (-1)*DIL)*EE;
    #pragma unroll
    for (int e=0;e<6;e++) curA[e] = *(const bf16x8*)(xs + aB + e*32);
  }
  __syncthreads();

  for (int tap=0; tap<9; tap++){
    int cur = tap & 1;
    ushort4 nxtW[9];
    bf16x8 nxtA[6];
    if (tap < 8){
      const ushort4* src = (const ushort4*)(ws + (size_t)(tap+1)*9216);
      #pragma unroll
      for (int k=0;k<9;k++) nxtW[k] = src[k*256+t];
      int ky = (tap+1)/3, kx = (tap+1)%3;
      int aB = aBase0 + ((ky-1)*DIL*PADW + (kx-1)*DIL)*EE;
      #pragma unroll
      for (int e=0;e<6;e++) nxtA[e] = *(const bf16x8*)(xs + aB + e*32);
    }
    const short* bl = &wlds[cur][0];
    #pragma unroll
    for (int e=0;e<6;e++){
      bf16x8 b0 = *(const bf16x8*)(bl + (e*3+0)*512 + lane*8);
      bf16x8 b1 = *(const bf16x8*)(bl + (e*3+1)*512 + lane*8);
      bf16x8 b2 = *(const bf16x8*)(bl + (e*3+2)*512 + lane*8);
      acc0 = __builtin_amdgcn_mfma_f32_16x16x32_bf16(curA[e], b0, acc0, 0,0,0);
      acc1 = __builtin_amdgcn_mfma_f32_16x16x32_bf16(curA[e], b1, acc1, 0,0,0);
      acc2 = __builtin_amdgcn_mfma_f32_16x16x32_bf16(curA[e], b2, acc2, 0,0,0);
    }
    if (tap < 8){
      ushort4* dst = (ushort4*)(&wlds[cur^1][0]);
      #pragma unroll
      for (int k=0;k<9;k++) dst[k*256+t] = nxtW[k];
      #pragma unroll
      for (int e=0;e<6;e++) curA[e] = nxtA[e];
    }
    __syncthreads();
  }

  int px0 = y*64 + wv*16 + kg*4;
  #pragma unroll
  for (int nt=0; nt<3; nt++){
    f32x4 a = (nt==0)?acc0:((nt==1)?acc1:acc2);
    int eo = eoB*48 + nt*16 + m;
    float add=0.0f, scale=0.0f, sh=0.0f;
    if (FUSE){ scale = bnw[eo]*rsqrtf(1.0f+1e-5f); sh = bnb[eo]; }
    else add = bias[eo];
    #pragma unroll
    for (int r=0;r<4;r++){
      float v = a[r];
      if (FUSE) v = fmaxf(v*scale + sh, 0.0f);
      else v += add;
      out[((size_t)(b*HWp) + px0 + r)*EE + eo] = v;
    }
  }
}

// ---------------- gather easy + in-projection via split-bf16 MFMA ----------------
__global__ __launch_bounds__(256) void k_inproj(const float* __restrict__ hid, const int* easy_idx,
        const unsigned short* __restrict__ wthi, const unsigned short* __restrict__ wtlo,
        float* __restrict__ xh, float* __restrict__ zb){
  int lane = threadIdx.x & 63, wv = threadIdx.x >> 6;
  int m = lane & 15, kg = lane >> 4;
  int bid = blockIdx.x;
  int b = bid >> 5; int l0 = (bid & 31)*64 + wv*16;
  int nq = blockIdx.y;
  int row = easy_idx[b*LEc + l0 + m];
  const float* srcp = hid + (size_t)(b*HWp + row)*EE + kg*8;
  bf16x8 Ah[6], Al[6];
  #pragma unroll
  for (int ks=0; ks<6; ks++){
    const float* sp = srcp + ks*32;
    #pragma unroll
    for (int q=0;q<8;q++){
      float v = sp[q];
      unsigned short hh, ll; split_bf16(v, hh, ll);
      Ah[ks][q] = (short)hh; Al[ks][q] = (short)ll;
    }
  }
  const short* wh = (const short*)wthi;
  const short* wl = (const short*)wtlo;
  for (int ntile=0; ntile<12; ntile++){
    int nt = nq*12 + ntile;
    const short* ph = wh + (size_t)nt*3072 + lane*8;
    const short* pl = wl + (size_t)nt*3072 + lane*8;
    f32x4 acc = {0,0,0,0};
    #pragma unroll
    for (int ks=0; ks<6; ks++){
      bf16x8 Bh = *(const bf16x8*)(ph + ks*512);
      bf16x8 Bl = *(const bf16x8*)(pl + ks*512);
      acc = __builtin_amdgcn_mfma_f32_16x16x32_bf16(Ah[ks], Bh, acc, 0,0,0);
      acc = __builtin_amdgcn_mfma_f32_16x16x32_bf16(Al[ks], Bh, acc, 0,0,0);
      acc = __builtin_amdgcn_mfma_f32_16x16x32_bf16(Ah[ks], Bl, acc, 0,0,0);
      acc = __builtin_amdgcn_mfma_f32_16x16x32_bf16(Al[ks], Bl, acc, 0,0,0);
    }
    int dd = nt*16 + m;
    #pragma unroll
    for (int r=0;r<4;r++){
      int rb = b*LEc + l0 + kg*4 + r;
      float o = acc[r];
      if (dd < DIN) xh[(size_t)rb*DIN + dd] = o;
      else zb[(size_t)rb*DIN + (dd-DIN)] = o;
    }
  }
}

// ---------------- fused causal conv + dbl (wave-parallel) + dt ----------------
__global__ __launch_bounds__(128) void k_mpre(const float* xh, const float* cw, const float* cb,
                                              const float* xw, const float* dtw, const float* dtb_w,
                                              float* xc, float* bc, float* dtb){
  int row = blockIdx.x;          // B*LE
  int l = row & 2047;
  int t = threadIdx.x;
  __shared__ float sxc[DIN];
  __shared__ float spart[20][6];
  __shared__ float sdbl[20];
  for (int i=t; i<DIN; i+=128){
    const float* w = cw + i*KC;
    float s = cb[i];
    #pragma unroll
    for (int k=0;k<KC;k++){
      int ls = l - 3 + k;
      if (ls >= 0) s += w[k]*xh[(row-3+k)*DIN + i];
    }
    s = s * sigmoid_fast(s);
    sxc[i] = s;
    xc[row*DIN+i] = s;
  }
  __syncthreads();
  if (t < 120){
    int r = t / 6, u = t % 6;
    const float* w = xw + r*DIN + u*64;
    const float* sx = sxc + u*64;
    float a=0,b2=0,c=0,d2=0;
    #pragma unroll 4
    for (int i=0;i<64;i+=4){ a+=sx[i]*w[i]; b2+=sx[i+1]*w[i+1]; c+=sx[i+2]*w[i+2]; d2+=sx[i+3]*w[i+3]; }
    spart[r][u] = a+b2+c+d2;
  }
  __syncthreads();
  if (t < 20){
    float o = spart[t][0]+spart[t][1]+spart[t][2]+spart[t][3]+spart[t][4]+spart[t][5];
    sdbl[t] = o;
    if (t >= DTR) bc[row*8 + (t-DTR)] = o;
  }
  __syncthreads();
  for (int i=t; i<DIN; i+=128){
    const float* w = dtw + i*DTR;
    float s = dtb_w[i];
    #pragma unroll
    for (int k=0;k<DTR;k++) s += sdbl[k]*w[k];
    dtb[row*DIN+i] = softplus_f(s);
  }
}

// ---------------- chunked selective scan (coalesced dch-across-threads) ----------------
__global__ void k_scanA(const float* dt, const float* xc, const float* bc, const float* Alog, float* chnk){
  int g = blockIdx.x*256+threadIdx.x;    // B*NCH*DIN
  int dch = g % DIN; int c = (g/DIN) % NCH; int b = g/(DIN*NCH);
  float A[4], P[4]={1,1,1,1}, h[4]={0,0,0,0};
  #pragma unroll
  for (int n=0;n<4;n++) A[n] = -__expf(Alog[dch*DST+n]);
  int lbase = b*LEc + c*CLEN;
  for (int s=0;s<CLEN;s++){
    int base = lbase + s;
    float dtv = dt[base*DIN + dch];
    float xcv = xc[base*DIN + dch];
    float dx = dtv*xcv;
    #pragma unroll
    for (int n=0;n<4;n++){
      float dA = __expf(dtv*A[n]);
      float Bn = bc[base*8 + n];
      h[n] = dA*h[n] + dx*Bn;
      P[n] *= dA;
    }
  }
  float* o = chnk + (size_t)g*8;
  #pragma unroll
  for (int n=0;n<4;n++){ o[n]=P[n]; o[4+n]=h[n]; }
}

__global__ void k_scanB(const float* chnk, float* hin){
  int g = blockIdx.x*256+threadIdx.x;
  if (g >= BB*DIN) return;
  int dch = g % DIN; int b = g / DIN;
  float h0=0,h1=0,h2=0,h3=0;
  for (int cb=0; cb<NCH/8; cb++){
    float4 P[8], Hl[8];
    #pragma unroll
    for (int u=0;u<8;u++){
      const float4* cp = (const float4*)(chnk + (size_t)((b*NCH + cb*8+u)*DIN + dch)*8);
      P[u] = cp[0]; Hl[u] = cp[1];
    }
    #pragma unroll
    for (int u=0;u<8;u++){
      int idx = (b*NCH + cb*8+u)*DIN + dch;
      float4 hv; hv.x=h0; hv.y=h1; hv.z=h2; hv.w=h3;
      *(float4*)(hin + (size_t)idx*4) = hv;
      h0 = P[u].x*h0 + Hl[u].x;
      h1 = P[u].y*h1 + Hl[u].y;
      h2 = P[u].z*h2 + Hl[u].z;
      h3 = P[u].w*h3 + Hl[u].w;
    }
  }
}

__global__ void k_scanC(const float* dt, const float* xc, const float* zb, const float* bc, const float* Alog,
                        const float* Dw, const float* hin, float* yb){
  int g = blockIdx.x*256+threadIdx.x;    // B*NCH*DIN
  int dch = g % DIN; int c = (g/DIN) % NCH; int b = g/(DIN*NCH);
  float A[4], h[4];
  #pragma unroll
  for (int n=0;n<4;n++){ A[n] = -__expf(Alog[dch*DST+n]); h[n] = hin[(size_t)g*4+n]; }
  float Dv = Dw[dch];
  int lbase = b*LEc + c*CLEN;
  for (int s=0;s<CLEN;s++){
    int base = lbase + s;
    float dtv = dt[base*DIN+dch];
    float xcv = xc[base*DIN+dch];
    float zv  = zb[base*DIN+dch];
    float dx = dtv*xcv;
    float y = 0.0f;
    #pragma unroll
    for (int n=0;n<4;n++){
      float dA = __expf(dtv*A[n]);
      h[n] = dA*h[n] + dx*bc[base*8+n];
      y += h[n]*bc[base*8+4+n];
    }
    y = (y + Dv*xcv) * (zv * sigmoid_fast(zv));
    yb[base*DIN + dch] = y;
  }
}

// ---------------- out-projection via split-bf16 MFMA + scatter ----------------
__global__ __launch_bounds__(256) void k_outproj(const float* __restrict__ yb, const int* easy_idx,
        const unsigned short* __restrict__ wthi, const unsigned short* __restrict__ wtlo,
        float* __restrict__ hidden){
  int lane = threadIdx.x & 63, wv = threadIdx.x >> 6;
  int m = lane & 15, kg = lane >> 4;
  int bid = blockIdx.x;
  int b = bid >> 5; int l0 = (bid & 31)*64 + wv*16;
  int nq = blockIdx.y;
  const float* srcp = yb + (size_t)(b*LEc + l0 + m)*DIN + kg*8;
  bf16x8 Ah[12], Al[12];
  #pragma unroll
  for (int ks=0; ks<12; ks++){
    const float* sp = srcp + ks*32;
    #pragma unroll
    for (int q=0;q<8;q++){
      unsigned short hh, ll; split_bf16(sp[q], hh, ll);
      Ah[ks][q] = (short)hh; Al[ks][q] = (short)ll;
    }
  }
  int rows[4];
  #pragma unroll
  for (int r=0;r<4;r++) rows[r] = easy_idx[b*LEc + l0 + kg*4 + r];
  const short* wh = (const short*)wthi;
  const short* wl = (const short*)wtlo;
  for (int ntile=0; ntile<3; ntile++){
    int nt = nq*3 + ntile;
    const short* ph = wh + (size_t)nt*6144 + lane*8;
    const short* pl = wl + (size_t)nt*6144 + lane*8;
    f32x4 acc = {0,0,0,0};
    #pragma unroll
    for (int ks=0; ks<12; ks++){
      bf16x8 Bh = *(const bf16x8*)(ph + ks*512);
      bf16x8 Bl = *(const bf16x8*)(pl + ks*512);
      acc = __builtin_amdgcn_mfma_f32_16x16x32_bf16(Ah[ks], Bh, acc, 0,0,0);
      acc = __builtin_amdgcn_mfma_f32_16x16x32_bf16(Al[ks], Bh, acc, 0,0,0);
      acc = __builtin_amdgcn_mfma_f32_16x16x32_bf16(Ah[ks], Bl, acc, 0,0,0);
      acc = __builtin_amdgcn_mfma_f32_16x16x32_bf16(Al[ks], Bl, acc, 0,0,0);
    }
    int eo = nt*16 + m;
    #pragma unroll
    for (int r=0;r<4;r++)
      hidden[(size_t)(b*HWp + rows[r])*EE + eo] = acc[r];
  }
}

// ---------------- final LayerNorm -> bf16 padded conv-input ----------------
__global__ __launch_bounds__(192) void k_ln(const float* hidden, const float* residual,
                                            const float* lnw, const float* lnb,
                                            __hip_bfloat16* __restrict__ xpad){
  int row = blockIdx.x; int e = threadIdx.x;
  int o = row*EE + e;
  float v = hidden[o] + residual[o];
  __shared__ float redA[3], redB[3];
  float s = v;
  #pragma unroll
  for (int m=32;m>0;m>>=1) s += __shfl_xor(s, m, 64);
  if ((e&63)==0) redA[e>>6] = s;
  __syncthreads();
  float mu = (redA[0]+redA[1]+redA[2])*(1.0f/EE);
  float dv = v - mu;
  float s2 = dv*dv;
  #pragma unroll
  for (int m=32;m>0;m>>=1) s2 += __shfl_xor(s2, m, 64);
  if ((e&63)==0) redB[e>>6] = s2;
  __syncthreads();
  float var = (redB[0]+redB[1]+redB[2])*(1.0f/EE);
  float o2 = dv*rsqrtf(var + 1e-5f)*lnw[e] + lnb[e];
  int b = row >> 12; int p = row & 4095; int y = p >> 6; int x = p & 63;
  xpad[((size_t)(b*PADW + y + PADP)*PADW + (x + PADP))*EE + e] = __float2bfloat16(o2);
}

// ---------------- classifier 1x1 (192 -> 9) ----------------
__global__ __launch_bounds__(64) void k_cls(const float* h1, const float* cls_w, const float* cls_b, float* out){
  __shared__ float wsm[NCc][EE];
  int t = threadIdx.x;
  for (int i=t; i<NCc*EE; i+=64){ wsm[i/EE][i%EE] = cls_w[i]; }
  __syncthreads();
  int g = blockIdx.x*64 + t;           // B*HW, grid 128
  int p = g & 4095; int b = g >> 12;
  const float4* hrow = (const float4*)(h1 + (size_t)g*EE);
  float acc[NCc];
  #pragma unroll
  for (int n=0;n<NCc;n++) acc[n] = cls_b[n];
  for (int c4=0;c4<EE/4;c4++){
    float4 h = hrow[c4];
    #pragma unroll
    for (int n=0;n<NCc;n++){
      const float4 wv = *(const float4*)(&wsm[n][c4*4]);
      acc[n] += h.x*wv.x + h.y*wv.y + h.z*wv.z + h.w*wv.w;
    }
  }
  #pragma unroll
  for (int n=0;n<NCc;n++)
    out[((size_t)b*NCc + n)*HWp + p] = acc[n];
}

// ================= host launch =================
extern "C" void kernel_launch(void* const* d_in, const int* in_sizes, int n_in,
                              void* d_out, int out_size, void* d_ws, size_t ws_size,
                              hipStream_t stream) {
  const float* x          = (const float*)d_in[0];
  const float* sp_w       = (const float*)d_in[2];
  const float* sp_b       = (const float*)d_in[3];
  const float* c0_w       = (const float*)d_in[4];
  const float* c0_b       = (const float*)d_in[5];
  const float* blk_norm_w = (const float*)d_in[6];
  const float* blk_conv_w = (const float*)d_in[7];
  const float* blk_conv_b = (const float*)d_in[8];
  const float* m_in_w     = (const float*)d_in[9];
  const float* m_conv_w   = (const float*)d_in[10];
  const float* m_conv_b   = (const float*)d_in[11];
  const float* m_x_w      = (const float*)d_in[12];
  const float* m_dt_w     = (const float*)d_in[13];
  const float* m_dt_b     = (const float*)d_in[14];
  const float* m_Alog     = (const float*)d_in[15];
  const float* m_D        = (const float*)d_in[16];
  const float* m_out_w    = (const float*)d_in[17];
  const float* ln_w       = (const float*)d_in[18];
  const float* ln_b       = (const float*)d_in[19];
  const float* h_conv_w   = (const float*)d_in[20];
  const float* h_bn_w     = (const float*)d_in[21];
  const float* h_bn_b     = (const float*)d_in[22];
  const float* h_cls_w    = (const float*)d_in[23];
  const float* h_cls_b    = (const float*)d_in[24];

  float* out_sp     = (float*)d_out;          // B*HW
  float* out_logits = (float*)d_out + BB*HWp; // B*NC*HW

  // workspace carve-up (floats)
  float* w = (float*)d_ws;
  size_t off = 0;
  auto alloc = [&](size_t n){ float* p = w + off; off += (n + 63) & ~size_t(63); return p; };
  float* res2    = alloc(BB*HWp*CH);
  float* feats   = alloc(BB*HWp*CH);
  float* scores  = alloc(BB*HWp);
  float* bnorm   = alloc(BB*SAMPLE);
  float* hidden  = alloc(BB*HWp*EE);
  float* residual= alloc(BB*HWp*EE);
  float* hid2    = alloc(BB*HWp*EE);
  float* xh      = alloc(BB*LEc*DIN);
  float* zb      = alloc(BB*LEc*DIN);
  float* xc      = alloc(BB*LEc*DIN);
  float* dtb     = alloc(BB*LEc*DIN);
  float* yb      = alloc(BB*LEc*DIN);
  float* bcbuf   = alloc(BB*LEc*8);
  float* pval    = alloc(BB*HWp*NSPLIT);
  float* chnk    = alloc((size_t)BB*NCH*DIN*8);
  float* hin     = alloc((size_t)BB*NCH*DIN*4);
  __hip_bfloat16* wtb_blk  = (__hip_bfloat16*)alloc(SZ_WTBLK_BF/2);
  __hip_bfloat16* wtb_head = (__hip_bfloat16*)alloc(SZ_WTHEAD_BF/2);
  unsigned short* wtb_in_hi = (unsigned short*)alloc(SZ_WTIN/2);
  unsigned short* wtb_in_lo = (unsigned short*)alloc(SZ_WTIN/2);
  unsigned short* wtb_out_hi = (unsigned short*)alloc(SZ_WTOUT/2);
  unsigned short* wtb_out_lo = (unsigned short*)alloc(SZ_WTOUT/2);
  unsigned short* wtc0_hi = (unsigned short*)alloc(SZ_WTC0/2);
  unsigned short* wtc0_lo = (unsigned short*)alloc(SZ_WTC0/2);
  __hip_bfloat16* xpad     = (__hip_bfloat16*)alloc(BB*PADW*PADW*EE/2);
  unsigned short* fhi    = (unsigned short*)alloc(BB*HWp*CH/2);
  unsigned short* flo    = (unsigned short*)alloc(BB*HWp*CH/2);
  unsigned short* bankhi = (unsigned short*)alloc(BB*SAMPLE*CH/2);
  unsigned short* banklo = (unsigned short*)alloc(BB*SAMPLE*CH/2);
  int* pidx       = (int*)alloc(BB*HWp*NSPLIT);
  int* idx_sorted = (int*)alloc(BB*SAMPLE);
  int* ranks      = (int*)alloc(BB*HWp);
  int* easy_idx   = (int*)alloc(BB*LEc);
  if (off*sizeof(float) > ws_size) return;  // workspace too small -> fail loud via validation

  prep_weights<<<(SZ_WT_TOTAL+NXPI+NRANKS+255)/256, 256, 0, stream>>>(
      blk_conv_w, h_conv_w, m_in_w, m_out_w, c0_w,
      wtb_blk, wtb_head, wtb_in_hi, wtb_in_lo, wtb_out_hi, wtb_out_lo,
      wtc0_hi, wtc0_lo, (int*)xpad, ranks);
  k_prep2<<<BB*HWp/32, 256, 0, stream>>>(x, sp_w, sp_b, res2, feats, fhi, flo, scores, out_sp);
  k_rank2<<<dim3(16,16,BB), 256, 0, stream>>>(scores, ranks);
  k_easy<<<BB, 1024, 0, stream>>>(ranks, idx_sorted, easy_idx);
  k_bank<<<BB*SAMPLE/64, 64, 0, stream>>>(feats, idx_sorted, bnorm, bankhi, banklo);
  k_nn_mfma<<<dim3(HWp/64, NSPLIT, BB), 256, 0, stream>>>(fhi, flo, bankhi, banklo, bnorm,
                                                          idx_sorted, pval, pidx);
  k_c0<<<dim3(BB*HWp/64, 4), 256, 0, stream>>>(res2, feats, idx_sorted, pval, pidx,
                                               wtc0_hi, wtc0_lo, c0_b, hidden);

  for (int d=0; d<2; d++){
    k_rms<<<BB*HWp, 192, 0, stream>>>(hidden, residual, xpad, blk_norm_w + d*EE, d==0);
    k_conv3s<1,0><<<dim3(BB*64,4), 256, 0, stream>>>(xpad, wtb_blk + d*9*EE*EE,
                                                     blk_conv_b + d*EE, nullptr, nullptr, hidden);
    k_inproj<<<dim3(BB*LEc/64, 4), 256, 0, stream>>>(hidden, easy_idx,
                                                     wtb_in_hi + (size_t)d*147456,
                                                     wtb_in_lo + (size_t)d*147456, xh, zb);
    k_mpre<<<BB*LEc, 128, 0, stream>>>(xh, m_conv_w + d*DIN*KC, m_conv_b + d*DIN,
                                       m_x_w + d*(DTR+2*DST)*DIN, m_dt_w + d*DIN*DTR, m_dt_b + d*DIN,
                                       xc, bcbuf, dtb);
    k_scanA<<<BB*NCH*DIN/256, 256, 0, stream>>>(dtb, xc, bcbuf, m_Alog + d*DIN*DST, chnk);
    k_scanB<<<(BB*DIN+255)/256, 256, 0, stream>>>(chnk, hin);
    k_scanC<<<BB*NCH*DIN/256, 256, 0, stream>>>(dtb, xc, zb, bcbuf, m_Alog + d*DIN*DST,
                                                m_D + d*DIN, hin, yb);
    k_outproj<<<dim3(BB*LEc/64, 4), 256, 0, stream>>>(yb, easy_idx,
                                                      wtb_out_hi + (size_t)d*73728,
                                                      wtb_out_lo + (size_t)d*73728, hidden);
  }

  k_ln<<<BB*HWp, 192, 0, stream>>>(hidden, residual, ln_w, ln_b, xpad);
  k_conv3s<3,1><<<dim3(BB*64,4), 256, 0, stream>>>(xpad, wtb_head, nullptr, h_bn_w, h_bn_b, hid2);
  k_cls<<<BB*HWp/64, 64, 0, stream>>>(hid2, h_cls_w, h_cls_b, out_logits);
}